// Round 12
// baseline (172.225 us; speedup 1.0000x reference)
//
#include <hip/hip_runtime.h>
#include <math.h>

#define N_NODES 40000
#define N_EDGES 640000
#define D 128
#define D_OUT 64
#define SCAN_NBLK 157   // ceil(40000/256)

typedef __attribute__((ext_vector_type(8))) short short8v;   // 8 bf16 = 4 VGPR
typedef __attribute__((ext_vector_type(8))) unsigned short ushort8v;
typedef __attribute__((ext_vector_type(4))) float f32x4;

__device__ __forceinline__ float bf2f(unsigned short u) {
    return __uint_as_float(((unsigned int)u) << 16);
}
__device__ __forceinline__ unsigned short f2bf(float f) {
    unsigned int u = __float_as_uint(f);
    return (unsigned short)((u + 0x7FFFu + ((u >> 16) & 1u)) >> 16);  // RNE
}

// ---- fused prep: bf16 converts + W transposes + degree histogram ----
// (deg/cnt pre-zeroed by hipMemsetAsync)
__global__ __launch_bounds__(256) void k_prep(const float* __restrict__ X,
                                              const float* __restrict__ W1,
                                              const float* __restrict__ W2,
                                              const float* __restrict__ Wp,
                                              const int* __restrict__ tgt,
                                              int* __restrict__ deg,
                                              unsigned short* __restrict__ x_bf,
                                              unsigned short* __restrict__ W1t,
                                              unsigned short* __restrict__ W2t,
                                              unsigned short* __restrict__ Wpt) {
    int i = blockIdx.x * 256 + threadIdx.x;   // grid = 5000 blocks
    if (i < 128 * 128) {            // Wt[n*K+k] = W[k*N+n]
        int n = i >> 7, k = i & 127;
        W1t[i] = f2bf(W1[(size_t)k * 128 + n]);
        W2t[i] = f2bf(W2[(size_t)k * 128 + n]);
    }
    if (i < 384 * 64) {
        int n = i / 384, k = i - n * 384;
        Wpt[i] = f2bf(Wp[(size_t)k * 64 + n]);
    }
    if (i < N_NODES * D / 4) {
        float4 v = ((const float4*)X)[i];
        ushort4 o;
        o.x = f2bf(v.x); o.y = f2bf(v.y); o.z = f2bf(v.z); o.w = f2bf(v.w);
        ((ushort4*)x_bf)[i] = o;
    }
    if (i < N_EDGES) atomicAdd(&deg[tgt[i]], 1);
}

// ---------------- CSR scan level 1 (local) + dis ----------------
__global__ __launch_bounds__(256) void k_scan1(const int* __restrict__ deg,
                                               int* __restrict__ row_ptr,
                                               int* __restrict__ partials,
                                               float* __restrict__ dis) {
    __shared__ int s[256];
    int t = threadIdx.x;
    int i = blockIdx.x * 256 + t;
    int v = (i < N_NODES) ? deg[i] : 0;
    if (i < N_NODES) dis[i] = rsqrtf((float)v + 1.0f);  // +1 self-loop
    s[t] = v;
    __syncthreads();
    #pragma unroll
    for (int off = 1; off < 256; off <<= 1) {
        int u = (t >= off) ? s[t - off] : 0;
        __syncthreads();
        s[t] += u;
        __syncthreads();
    }
    if (i < N_NODES) row_ptr[i] = s[t] - v;      // block-local exclusive
    if (t == 255) partials[blockIdx.x] = s[255];
}

// ---------------- shared MFMA GEMM body (Wt: [128 n][128 k] bf16) ----------------
// Epilogue scales row r by dis[r]:  C = bf16( dis[row] * (A @ W) )
__device__ __forceinline__ void gemm128_body(int blk, int nblk,
                                             const unsigned short* __restrict__ A,
                                             const unsigned short* __restrict__ Wt,
                                             const float* __restrict__ dis,
                                             unsigned short* __restrict__ C) {
    int w  = threadIdx.x >> 6;
    int l  = threadIdx.x & 63;
    int lr = l & 15;
    int lk = l >> 4;

    short8v wf[2][4];
    #pragma unroll
    for (int nt = 0; nt < 2; ++nt) {
        int n = w * 32 + nt * 16 + lr;
        #pragma unroll
        for (int kc = 0; kc < 4; ++kc)
            wf[nt][kc] = *(const short8v*)(Wt + (size_t)n * 128 + kc * 32 + lk * 8);
    }

    for (int mt = blk; mt < 2500; mt += nblk) {
        int m0 = mt * 16;
        f32x4 acc0 = {0.f, 0.f, 0.f, 0.f};
        f32x4 acc1 = {0.f, 0.f, 0.f, 0.f};
        #pragma unroll
        for (int kc = 0; kc < 4; ++kc) {
            short8v a = *(const short8v*)(A + (size_t)(m0 + lr) * 128 + kc * 32 + lk * 8);
            acc0 = __builtin_amdgcn_mfma_f32_16x16x32_bf16(a, wf[0][kc], acc0, 0, 0, 0);
            acc1 = __builtin_amdgcn_mfma_f32_16x16x32_bf16(a, wf[1][kc], acc1, 0, 0, 0);
        }
        int row = m0 + lk * 4;
        int c0  = w * 32 + lr;
        #pragma unroll
        for (int r = 0; r < 4; ++r) {
            float dr = dis[row + r];
            C[(size_t)(row + r) * 128 + c0]      = f2bf(acc0[r] * dr);
            C[(size_t)(row + r) * 128 + c0 + 16] = f2bf(acc1[r] * dr);
        }
    }
}

__global__ __launch_bounds__(256) void k_mfma_gemm(const unsigned short* __restrict__ A,
                                                   const unsigned short* __restrict__ Wt,
                                                   const float* __restrict__ dis,
                                                   unsigned short* __restrict__ C) {
    gemm128_body(blockIdx.x, gridDim.x, A, Wt, dis, C);
}

// ---- fused dispatch: blocks 0-2499 CSR-scatter (+scan2 in LDS), 2500-3749 gemm1 --
__global__ __launch_bounds__(256) void k_scatter_gemm(
    const int* __restrict__ tgt, const int* __restrict__ src,
    const int* __restrict__ row_ptr_loc, const int* __restrict__ partials,
    int* __restrict__ row_ptr_g, int* __restrict__ cnt,
    int* __restrict__ col,
    const unsigned short* __restrict__ A, const unsigned short* __restrict__ Wt,
    const float* __restrict__ dis, unsigned short* __restrict__ C)
{
    if (blockIdx.x < 2500) {
        // per-block exclusive prefix of partials (replaces the k_scan2 dispatch)
        __shared__ int pre[256];
        int t = threadIdx.x;
        int v = (t < SCAN_NBLK) ? partials[t] : 0;
        pre[t] = v;
        __syncthreads();
        #pragma unroll
        for (int off = 1; off < 256; off <<= 1) {
            int u = (t >= off) ? pre[t - off] : 0;
            __syncthreads();
            pre[t] += u;
            __syncthreads();
        }
        int incl = pre[t];
        __syncthreads();
        pre[t] = incl - v;                       // exclusive
        __syncthreads();

        int e = blockIdx.x * 256 + t;
        if (e <= N_NODES) {
            if (e < N_NODES) row_ptr_g[e] = row_ptr_loc[e] + pre[e >> 8];
            else             row_ptr_g[N_NODES] = N_EDGES;
        }
        if (e >= N_EDGES) return;
        int tg = tgt[e];
        int pos = row_ptr_loc[tg] + pre[tg >> 8] + atomicAdd(&cnt[tg], 1);
        col[pos] = src[e];
    } else {
        gemm128_body(blockIdx.x - 2500, 1250, A, Wt, dis, C);
    }
}

// ---------------- MFMA final: out[40000 x 64] = [x,h1,h2]_bf16 @ Wp + bp ------
__global__ __launch_bounds__(256) void k_mfma_final(const unsigned short* __restrict__ xbf,
                                                    const unsigned short* __restrict__ h1bf,
                                                    const unsigned short* __restrict__ h2bf,
                                                    const unsigned short* __restrict__ Wpt,
                                                    const float* __restrict__ bp,
                                                    float* __restrict__ out) {
    int w  = threadIdx.x >> 6;
    int l  = threadIdx.x & 63;
    int lr = l & 15;
    int lk = l >> 4;

    short8v wf[12];
    {
        int n = w * 16 + lr;
        #pragma unroll
        for (int kc = 0; kc < 12; ++kc)
            wf[kc] = *(const short8v*)(Wpt + (size_t)n * 384 + kc * 32 + lk * 8);
    }
    const unsigned short* srcs[3] = {xbf, h1bf, h2bf};
    float bb = bp[w * 16 + lr];

    for (int mt = blockIdx.x; mt < 2500; mt += gridDim.x) {
        int m0 = mt * 16;
        f32x4 acc = {0.f, 0.f, 0.f, 0.f};
        #pragma unroll
        for (int kc = 0; kc < 12; ++kc) {
            const unsigned short* S = srcs[kc >> 2];
            short8v a = *(const short8v*)(S + (size_t)(m0 + lr) * 128 + (kc & 3) * 32 + lk * 8);
            acc = __builtin_amdgcn_mfma_f32_16x16x32_bf16(a, wf[kc], acc, 0, 0, 0);
        }
        int row = m0 + lk * 4;
        int c   = w * 16 + lr;
        #pragma unroll
        for (int r = 0; r < 4; ++r)
            out[(size_t)(row + r) * 64 + c] = acc[r] + bb;
    }
}

// ---------------- fused CSR aggregate + bias + self-loop + LayerNorm + ReLU ----
// Hs already scaled by dis[src]:  agg = b + dis[i]*(Hs[i] + Σ Hs[col]).
// 4 nodes per wave: 16 lanes per node, lane holds 8 dims (ushort8 = 16B load).
// Records are bare 4B col indices; 4 per aligned int4 load.
__global__ __launch_bounds__(256) void k_agg_ln(const unsigned short* __restrict__ Hs,
                                                const float* __restrict__ dis,
                                                const int* __restrict__ row_ptr,
                                                const int* __restrict__ col,
                                                const float* __restrict__ b,
                                                const float* __restrict__ g,
                                                const float* __restrict__ be,
                                                unsigned short* __restrict__ OUT) {
    int lh = threadIdx.x & 15;                 // dim group: 8 dims
    int i  = blockIdx.x * 16 + (threadIdx.x >> 4);
    if (i >= N_NODES) return;

    float a[8];
    {   // self term: dis^2*H = dis*Hs  -> accumulate Hs[i], scale at end
        ushort8v v = *(const ushort8v*)(Hs + (size_t)i * D + lh * 8);
        #pragma unroll
        for (int j = 0; j < 8; ++j) a[j] = bf2f(v[j]);
    }

    int e   = row_ptr[i];
    int end = row_ptr[i + 1];
    while (e < end && (e & 3)) {                // peel to 16B-align col reads
        ushort8v v = *(const ushort8v*)(Hs + (size_t)col[e] * D + lh * 8);
        #pragma unroll
        for (int j = 0; j < 8; ++j) a[j] += bf2f(v[j]);
        ++e;
    }
    for (; e + 3 < end; e += 4) {               // 4 edges per int4 record load
        int4 p = *(const int4*)&col[e];
        ushort8v v0 = *(const ushort8v*)(Hs + (size_t)p.x * D + lh * 8);
        ushort8v v1 = *(const ushort8v*)(Hs + (size_t)p.y * D + lh * 8);
        ushort8v v2 = *(const ushort8v*)(Hs + (size_t)p.z * D + lh * 8);
        ushort8v v3 = *(const ushort8v*)(Hs + (size_t)p.w * D + lh * 8);
        #pragma unroll
        for (int j = 0; j < 8; ++j) a[j] += bf2f(v0[j]);
        #pragma unroll
        for (int j = 0; j < 8; ++j) a[j] += bf2f(v1[j]);
        #pragma unroll
        for (int j = 0; j < 8; ++j) a[j] += bf2f(v2[j]);
        #pragma unroll
        for (int j = 0; j < 8; ++j) a[j] += bf2f(v3[j]);
    }
    for (; e < end; ++e) {
        ushort8v v = *(const ushort8v*)(Hs + (size_t)col[e] * D + lh * 8);
        #pragma unroll
        for (int j = 0; j < 8; ++j) a[j] += bf2f(v[j]);
    }

    // bias + dis scale, then LayerNorm over 128 dims + ReLU
    {
        float di = dis[i];
        const float4* b4 = (const float4*)(b + lh * 8);
        float4 bb0 = b4[0], bb1 = b4[1];
        a[0] = bb0.x + di * a[0]; a[1] = bb0.y + di * a[1];
        a[2] = bb0.z + di * a[2]; a[3] = bb0.w + di * a[3];
        a[4] = bb1.x + di * a[4]; a[5] = bb1.y + di * a[5];
        a[6] = bb1.z + di * a[6]; a[7] = bb1.w + di * a[7];
    }

    float s = 0.f;
    #pragma unroll
    for (int j = 0; j < 8; ++j) s += a[j];
    #pragma unroll
    for (int off = 8; off >= 1; off >>= 1) s += __shfl_xor(s, off);
    float mean = s * (1.0f / 128.0f);

    float vs = 0.f;
    #pragma unroll
    for (int j = 0; j < 8; ++j) { a[j] -= mean; vs += a[j] * a[j]; }
    #pragma unroll
    for (int off = 8; off >= 1; off >>= 1) vs += __shfl_xor(vs, off);
    float inv = rsqrtf(vs * (1.0f / 128.0f) + 1e-5f);

    const float4* g4 = (const float4*)(g + lh * 8);
    const float4* e4 = (const float4*)(be + lh * 8);
    float4 g0 = g4[0], g1 = g4[1], e0 = e4[0], e1 = e4[1];
    ushort8v o;
    o[0] = f2bf(fmaxf(a[0] * inv * g0.x + e0.x, 0.0f));
    o[1] = f2bf(fmaxf(a[1] * inv * g0.y + e0.y, 0.0f));
    o[2] = f2bf(fmaxf(a[2] * inv * g0.z + e0.z, 0.0f));
    o[3] = f2bf(fmaxf(a[3] * inv * g0.w + e0.w, 0.0f));
    o[4] = f2bf(fmaxf(a[4] * inv * g1.x + e1.x, 0.0f));
    o[5] = f2bf(fmaxf(a[5] * inv * g1.y + e1.y, 0.0f));
    o[6] = f2bf(fmaxf(a[6] * inv * g1.z + e1.z, 0.0f));
    o[7] = f2bf(fmaxf(a[7] * inv * g1.w + e1.w, 0.0f));
    *(ushort8v*)(OUT + (size_t)i * D + lh * 8) = o;
}

// ---------------- launcher ----------------
extern "C" void kernel_launch(void* const* d_in, const int* in_sizes, int n_in,
                              void* d_out, int out_size, void* d_ws, size_t ws_size,
                              hipStream_t stream) {
    const float* x   = (const float*)d_in[0];
    const int*   ei  = (const int*)  d_in[1];   // [2, E] int32
    const float* W1  = (const float*)d_in[2];
    const float* b1  = (const float*)d_in[3];
    const float* g1  = (const float*)d_in[4];
    const float* be1 = (const float*)d_in[5];
    const float* W2  = (const float*)d_in[6];
    const float* b2  = (const float*)d_in[7];
    const float* g2  = (const float*)d_in[8];
    const float* be2 = (const float*)d_in[9];
    const float* Wp  = (const float*)d_in[10];
    const float* bp  = (const float*)d_in[11];
    float* out = (float*)d_out;

    const int* tgt = ei;
    const int* src = ei + N_EDGES;

    char* ws = (char*)d_ws;
    int*   deg_i   = (int*)   ws;               ws += 40960 * 4;   // adjacent to cnt:
    int*   cnt     = (int*)   ws;               ws += 40960 * 4;   // one memset covers both
    int*   row_ptr = (int*)   ws;               ws += 41984 * 4;   // block-local scan
    int*   row_ptr_g = (int*) ws;               ws += 41984 * 4;   // globalized
    int*   partials= (int*)   ws;               ws += 256 * 4;
    int*   col     = (int*)   ws;               ws += (size_t)N_EDGES * 4;
    float* dis     = (float*) ws;               ws += 40960 * 4;
    unsigned short* x_bf   = (unsigned short*)ws; ws += (size_t)N_NODES * D * 2;
    unsigned short* tmp_bf = (unsigned short*)ws; ws += (size_t)N_NODES * D * 2;
    unsigned short* h1_bf  = (unsigned short*)ws; ws += (size_t)N_NODES * D * 2;
    unsigned short* h2_bf  = (unsigned short*)ws; ws += (size_t)N_NODES * D * 2;
    unsigned short* W1t    = (unsigned short*)ws; ws += 128 * 128 * 2;
    unsigned short* W2t    = (unsigned short*)ws; ws += 128 * 128 * 2;
    unsigned short* Wpt    = (unsigned short*)ws; ws += 384 * 64 * 2;

    const int B = 256;

    // zero deg+cnt (adjacent) with one async memset, then fused prep+degree
    hipMemsetAsync(deg_i, 0, 2 * 40960 * 4, stream);
    k_prep <<<5000, B, 0, stream>>>(x, W1, W2, Wp, tgt, deg_i, x_bf, W1t, W2t, Wpt);
    k_scan1<<<SCAN_NBLK, B, 0, stream>>>(deg_i, row_ptr, partials, dis);

    // ---- scatter (CSR, with in-LDS partials scan) + gemm1 (dis*(x@W1)) ----
    k_scatter_gemm<<<3750, B, 0, stream>>>(tgt, src, row_ptr, partials,
                                           row_ptr_g, cnt, col,
                                           x_bf, W1t, dis, tmp_bf);

    // ---- block 1 aggregate ----
    k_agg_ln<<<2500, B, 0, stream>>>(tmp_bf, dis, row_ptr_g, col, b1, g1, be1, h1_bf);

    // ---- block 2 ----
    k_mfma_gemm<<<1250, B, 0, stream>>>(h1_bf, W2t, dis, tmp_bf);
    k_agg_ln<<<2500, B, 0, stream>>>(tmp_bf, dis, row_ptr_g, col, b2, g2, be2, h2_bf);

    // ---- jumping-knowledge concat + projection ----
    k_mfma_final<<<1250, B, 0, stream>>>(x_bf, h1_bf, h2_bf, Wpt, bp, out);
}

// Round 14
// 149.565 us; speedup vs baseline: 1.1515x; 1.1515x over previous
//
#include <hip/hip_runtime.h>
#include <math.h>

#define N_NODES 40000
#define N_EDGES 640000
#define D 128
#define D_OUT 64
#define SCAN_NBLK 157   // ceil(40000/256)

typedef __attribute__((ext_vector_type(8))) short short8v;   // 8 bf16 = 4 VGPR
typedef __attribute__((ext_vector_type(8))) unsigned short ushort8v;
typedef __attribute__((ext_vector_type(4))) float f32x4;

__device__ __forceinline__ float bf2f(unsigned short u) {
    return __uint_as_float(((unsigned int)u) << 16);
}
__device__ __forceinline__ unsigned short f2bf(float f) {
    unsigned int u = __float_as_uint(f);
    return (unsigned short)((u + 0x7FFFu + ((u >> 16) & 1u)) >> 16);  // RNE
}

// ---- fused prep: bf16 converts + W transposes + degree histogram + edge rank ----
// (deg pre-zeroed by hipMemsetAsync; atomic old-value = edge's rank within its row)
__global__ __launch_bounds__(256) void k_prep(const float* __restrict__ X,
                                              const float* __restrict__ W1,
                                              const float* __restrict__ W2,
                                              const float* __restrict__ Wp,
                                              const int* __restrict__ tgt,
                                              int* __restrict__ deg,
                                              int* __restrict__ rank,
                                              unsigned short* __restrict__ x_bf,
                                              unsigned short* __restrict__ W1t,
                                              unsigned short* __restrict__ W2t,
                                              unsigned short* __restrict__ Wpt) {
    int i = blockIdx.x * 256 + threadIdx.x;   // grid = 5000 blocks
    if (i < 128 * 128) {            // Wt[n*K+k] = W[k*N+n]
        int n = i >> 7, k = i & 127;
        W1t[i] = f2bf(W1[(size_t)k * 128 + n]);
        W2t[i] = f2bf(W2[(size_t)k * 128 + n]);
    }
    if (i < 384 * 64) {
        int n = i / 384, k = i - n * 384;
        Wpt[i] = f2bf(Wp[(size_t)k * 64 + n]);
    }
    if (i < N_NODES * D / 4) {
        float4 v = ((const float4*)X)[i];
        ushort4 o;
        o.x = f2bf(v.x); o.y = f2bf(v.y); o.z = f2bf(v.z); o.w = f2bf(v.w);
        ((ushort4*)x_bf)[i] = o;
    }
    if (i < N_EDGES) rank[i] = atomicAdd(&deg[tgt[i]], 1);
}

// ---------------- CSR scan level 1 (local) + dis ----------------
__global__ __launch_bounds__(256) void k_scan1(const int* __restrict__ deg,
                                               int* __restrict__ row_ptr,
                                               int* __restrict__ partials,
                                               float* __restrict__ dis) {
    __shared__ int s[256];
    int t = threadIdx.x;
    int i = blockIdx.x * 256 + t;
    int v = (i < N_NODES) ? deg[i] : 0;
    if (i < N_NODES) dis[i] = rsqrtf((float)v + 1.0f);  // +1 self-loop
    s[t] = v;
    __syncthreads();
    #pragma unroll
    for (int off = 1; off < 256; off <<= 1) {
        int u = (t >= off) ? s[t - off] : 0;
        __syncthreads();
        s[t] += u;
        __syncthreads();
    }
    if (i < N_NODES) row_ptr[i] = s[t] - v;      // block-local exclusive
    if (t == 255) partials[blockIdx.x] = s[255];
}

// ---------------- shared MFMA GEMM body (Wt: [128 n][128 k] bf16) ----------------
// Epilogue scales row r by dis[r]:  C = bf16( dis[row] * (A @ W) )
__device__ __forceinline__ void gemm128_body(int blk, int nblk,
                                             const unsigned short* __restrict__ A,
                                             const unsigned short* __restrict__ Wt,
                                             const float* __restrict__ dis,
                                             unsigned short* __restrict__ C) {
    int w  = threadIdx.x >> 6;
    int l  = threadIdx.x & 63;
    int lr = l & 15;
    int lk = l >> 4;

    short8v wf[2][4];
    #pragma unroll
    for (int nt = 0; nt < 2; ++nt) {
        int n = w * 32 + nt * 16 + lr;
        #pragma unroll
        for (int kc = 0; kc < 4; ++kc)
            wf[nt][kc] = *(const short8v*)(Wt + (size_t)n * 128 + kc * 32 + lk * 8);
    }

    for (int mt = blk; mt < 2500; mt += nblk) {
        int m0 = mt * 16;
        f32x4 acc0 = {0.f, 0.f, 0.f, 0.f};
        f32x4 acc1 = {0.f, 0.f, 0.f, 0.f};
        #pragma unroll
        for (int kc = 0; kc < 4; ++kc) {
            short8v a = *(const short8v*)(A + (size_t)(m0 + lr) * 128 + kc * 32 + lk * 8);
            acc0 = __builtin_amdgcn_mfma_f32_16x16x32_bf16(a, wf[0][kc], acc0, 0, 0, 0);
            acc1 = __builtin_amdgcn_mfma_f32_16x16x32_bf16(a, wf[1][kc], acc1, 0, 0, 0);
        }
        int row = m0 + lk * 4;
        int c0  = w * 32 + lr;
        #pragma unroll
        for (int r = 0; r < 4; ++r) {
            float dr = dis[row + r];
            C[(size_t)(row + r) * 128 + c0]      = f2bf(acc0[r] * dr);
            C[(size_t)(row + r) * 128 + c0 + 16] = f2bf(acc1[r] * dr);
        }
    }
}

// ---- fused dispatch: blocks 0-2499 CSR-scatter (rank-based, atomic-free),
//      blocks 2500-3749 gemm1 = dis*(x@W1) ----
__global__ __launch_bounds__(256) void k_scatter_gemm(
    const int* __restrict__ tgt, const int* __restrict__ src,
    const int* __restrict__ row_ptr_loc, const int* __restrict__ partials,
    int* __restrict__ row_ptr_g, const int* __restrict__ rank,
    int* __restrict__ col,
    const unsigned short* __restrict__ A, const unsigned short* __restrict__ Wt,
    const float* __restrict__ dis, unsigned short* __restrict__ C)
{
    if (blockIdx.x < 2500) {
        // per-block exclusive prefix of partials (replaces a k_scan2 dispatch)
        __shared__ int pre[256];
        int t = threadIdx.x;
        int v = (t < SCAN_NBLK) ? partials[t] : 0;
        pre[t] = v;
        __syncthreads();
        #pragma unroll
        for (int off = 1; off < 256; off <<= 1) {
            int u = (t >= off) ? pre[t - off] : 0;
            __syncthreads();
            pre[t] += u;
            __syncthreads();
        }
        int incl = pre[t];
        __syncthreads();
        pre[t] = incl - v;                       // exclusive
        __syncthreads();

        int e = blockIdx.x * 256 + t;
        if (e <= N_NODES) {
            if (e < N_NODES) row_ptr_g[e] = row_ptr_loc[e] + pre[e >> 8];
            else             row_ptr_g[N_NODES] = N_EDGES;
        }
        if (e >= N_EDGES) return;
        int tg = tgt[e];
        int pos = row_ptr_loc[tg] + pre[tg >> 8] + rank[e];  // no atomic
        col[pos] = src[e];
    } else {
        gemm128_body(blockIdx.x - 2500, 1250, A, Wt, dis, C);
    }
}

// ---------------- shared agg+LN body ----------------
// Hs pre-scaled by dis[src]:  row = LN( b + dis[i]*(Hs[i] + Σ Hs[col]) ) -> ReLU -> bf16x8
__device__ __forceinline__ ushort8v agg_ln_body(const unsigned short* __restrict__ Hs,
                                                const float* __restrict__ dis,
                                                const int* __restrict__ row_ptr,
                                                const int* __restrict__ col,
                                                const float* __restrict__ b,
                                                const float* __restrict__ g,
                                                const float* __restrict__ be,
                                                int i, int lh) {
    float a[8];
    {
        ushort8v v = *(const ushort8v*)(Hs + (size_t)i * D + lh * 8);
        #pragma unroll
        for (int j = 0; j < 8; ++j) a[j] = bf2f(v[j]);
    }

    int e   = row_ptr[i];
    int end = row_ptr[i + 1];
    while (e < end && (e & 3)) {                // peel to 16B-align col reads
        ushort8v v = *(const ushort8v*)(Hs + (size_t)col[e] * D + lh * 8);
        #pragma unroll
        for (int j = 0; j < 8; ++j) a[j] += bf2f(v[j]);
        ++e;
    }
    for (; e + 3 < end; e += 4) {               // 4 edges per int4 record load
        int4 p = *(const int4*)&col[e];
        ushort8v v0 = *(const ushort8v*)(Hs + (size_t)p.x * D + lh * 8);
        ushort8v v1 = *(const ushort8v*)(Hs + (size_t)p.y * D + lh * 8);
        ushort8v v2 = *(const ushort8v*)(Hs + (size_t)p.z * D + lh * 8);
        ushort8v v3 = *(const ushort8v*)(Hs + (size_t)p.w * D + lh * 8);
        #pragma unroll
        for (int j = 0; j < 8; ++j) a[j] += bf2f(v0[j]);
        #pragma unroll
        for (int j = 0; j < 8; ++j) a[j] += bf2f(v1[j]);
        #pragma unroll
        for (int j = 0; j < 8; ++j) a[j] += bf2f(v2[j]);
        #pragma unroll
        for (int j = 0; j < 8; ++j) a[j] += bf2f(v3[j]);
    }
    for (; e < end; ++e) {
        ushort8v v = *(const ushort8v*)(Hs + (size_t)col[e] * D + lh * 8);
        #pragma unroll
        for (int j = 0; j < 8; ++j) a[j] += bf2f(v[j]);
    }

    {
        float di = dis[i];
        const float4* b4 = (const float4*)(b + lh * 8);
        float4 bb0 = b4[0], bb1 = b4[1];
        a[0] = bb0.x + di * a[0]; a[1] = bb0.y + di * a[1];
        a[2] = bb0.z + di * a[2]; a[3] = bb0.w + di * a[3];
        a[4] = bb1.x + di * a[4]; a[5] = bb1.y + di * a[5];
        a[6] = bb1.z + di * a[6]; a[7] = bb1.w + di * a[7];
    }

    float s = 0.f;
    #pragma unroll
    for (int j = 0; j < 8; ++j) s += a[j];
    #pragma unroll
    for (int off = 8; off >= 1; off >>= 1) s += __shfl_xor(s, off);
    float mean = s * (1.0f / 128.0f);

    float vs = 0.f;
    #pragma unroll
    for (int j = 0; j < 8; ++j) { a[j] -= mean; vs += a[j] * a[j]; }
    #pragma unroll
    for (int off = 8; off >= 1; off >>= 1) vs += __shfl_xor(vs, off);
    float inv = rsqrtf(vs * (1.0f / 128.0f) + 1e-5f);

    const float4* g4 = (const float4*)(g + lh * 8);
    const float4* e4 = (const float4*)(be + lh * 8);
    float4 g0 = g4[0], g1 = g4[1], e0 = e4[0], e1 = e4[1];
    ushort8v o;
    o[0] = f2bf(fmaxf(a[0] * inv * g0.x + e0.x, 0.0f));
    o[1] = f2bf(fmaxf(a[1] * inv * g0.y + e0.y, 0.0f));
    o[2] = f2bf(fmaxf(a[2] * inv * g0.z + e0.z, 0.0f));
    o[3] = f2bf(fmaxf(a[3] * inv * g0.w + e0.w, 0.0f));
    o[4] = f2bf(fmaxf(a[4] * inv * g1.x + e1.x, 0.0f));
    o[5] = f2bf(fmaxf(a[5] * inv * g1.y + e1.y, 0.0f));
    o[6] = f2bf(fmaxf(a[6] * inv * g1.z + e1.z, 0.0f));
    o[7] = f2bf(fmaxf(a[7] * inv * g1.w + e1.w, 0.0f));
    return o;
}

// ---- block 1 aggregate + LN + ReLU -> h1_bf, FUSED gemm2: tmp2 = dis*(h1@W2) ----
// NOTE: output buffer tmp2 MUST differ from gather input Hs (inter-block WAR race).
__global__ __launch_bounds__(256) void k_agg_gemm2(const unsigned short* __restrict__ Hs,
                                                   const float* __restrict__ dis,
                                                   const int* __restrict__ row_ptr,
                                                   const int* __restrict__ col,
                                                   const float* __restrict__ b,
                                                   const float* __restrict__ g,
                                                   const float* __restrict__ be,
                                                   const unsigned short* __restrict__ W2t,
                                                   unsigned short* __restrict__ H1,
                                                   unsigned short* __restrict__ tmp2) {
    __shared__ __align__(16) unsigned short sh[16][136];
    int lh  = threadIdx.x & 15;
    int gno = threadIdx.x >> 4;
    int i   = blockIdx.x * 16 + gno;          // 2500*16 = 40000 exact

    ushort8v o = agg_ln_body(Hs, dis, row_ptr, col, b, g, be, i, lh);
    *(ushort8v*)(H1 + (size_t)i * D + lh * 8) = o;
    *(ushort8v*)&sh[gno][lh * 8] = o;
    __syncthreads();

    // gemm2 epilogue: 16x128 (LDS) @ W2t -> dis-scaled bf16 tmp2
    int w  = threadIdx.x >> 6;
    int l  = threadIdx.x & 63;
    int lr = l & 15;
    int lk = l >> 4;

    f32x4 acc0 = {0.f, 0.f, 0.f, 0.f};
    f32x4 acc1 = {0.f, 0.f, 0.f, 0.f};
    #pragma unroll
    for (int kc = 0; kc < 4; ++kc) {
        short8v a = *(const short8v*)&sh[lr][kc * 32 + lk * 8];
        short8v w0 = *(const short8v*)(W2t + (size_t)(w * 32 + lr) * 128 + kc * 32 + lk * 8);
        short8v w1 = *(const short8v*)(W2t + (size_t)(w * 32 + 16 + lr) * 128 + kc * 32 + lk * 8);
        acc0 = __builtin_amdgcn_mfma_f32_16x16x32_bf16(a, w0, acc0, 0, 0, 0);
        acc1 = __builtin_amdgcn_mfma_f32_16x16x32_bf16(a, w1, acc1, 0, 0, 0);
    }
    int row = blockIdx.x * 16 + lk * 4;
    int c0  = w * 32 + lr;
    #pragma unroll
    for (int r = 0; r < 4; ++r) {
        float dr = dis[row + r];
        tmp2[(size_t)(row + r) * 128 + c0]      = f2bf(acc0[r] * dr);
        tmp2[(size_t)(row + r) * 128 + c0 + 16] = f2bf(acc1[r] * dr);
    }
}

// ---- block 2 aggregate + LN + ReLU (h2 stays in LDS), FUSED final projection:
//      out = [x, h1, h2] @ Wp + bp.   h2 never touches global memory. ----
__global__ __launch_bounds__(256) void k_agg_final(const unsigned short* __restrict__ Hs,
                                                   const float* __restrict__ dis,
                                                   const int* __restrict__ row_ptr,
                                                   const int* __restrict__ col,
                                                   const float* __restrict__ b,
                                                   const float* __restrict__ g,
                                                   const float* __restrict__ be,
                                                   const unsigned short* __restrict__ xbf,
                                                   const unsigned short* __restrict__ h1bf,
                                                   const unsigned short* __restrict__ Wpt,
                                                   const float* __restrict__ bp,
                                                   float* __restrict__ out) {
    __shared__ __align__(16) unsigned short sh[16][136];
    int lh  = threadIdx.x & 15;
    int gno = threadIdx.x >> 4;
    int i   = blockIdx.x * 16 + gno;

    ushort8v o = agg_ln_body(Hs, dis, row_ptr, col, b, g, be, i, lh);
    *(ushort8v*)&sh[gno][lh * 8] = o;
    __syncthreads();

    // final epilogue: wave w owns out cols [w*16, w*16+16)
    int w  = threadIdx.x >> 6;
    int l  = threadIdx.x & 63;
    int lr = l & 15;
    int lk = l >> 4;
    int arow = blockIdx.x * 16 + lr;

    f32x4 acc = {0.f, 0.f, 0.f, 0.f};
    #pragma unroll
    for (int kc = 0; kc < 12; ++kc) {
        short8v a;
        if (kc < 4)       a = *(const short8v*)(xbf  + (size_t)arow * 128 + kc * 32 + lk * 8);
        else if (kc < 8)  a = *(const short8v*)(h1bf + (size_t)arow * 128 + (kc - 4) * 32 + lk * 8);
        else              a = *(const short8v*)&sh[lr][(kc - 8) * 32 + lk * 8];
        short8v wf = *(const short8v*)(Wpt + (size_t)(w * 16 + lr) * 384 + kc * 32 + lk * 8);
        acc = __builtin_amdgcn_mfma_f32_16x16x32_bf16(a, wf, acc, 0, 0, 0);
    }
    float bb = bp[w * 16 + lr];
    int row = blockIdx.x * 16 + lk * 4;
    int c   = w * 16 + lr;
    #pragma unroll
    for (int r = 0; r < 4; ++r)
        out[(size_t)(row + r) * 64 + c] = acc[r] + bb;
}

// ---------------- launcher ----------------
extern "C" void kernel_launch(void* const* d_in, const int* in_sizes, int n_in,
                              void* d_out, int out_size, void* d_ws, size_t ws_size,
                              hipStream_t stream) {
    const float* x   = (const float*)d_in[0];
    const int*   ei  = (const int*)  d_in[1];   // [2, E] int32
    const float* W1  = (const float*)d_in[2];
    const float* b1  = (const float*)d_in[3];
    const float* g1  = (const float*)d_in[4];
    const float* be1 = (const float*)d_in[5];
    const float* W2  = (const float*)d_in[6];
    const float* b2  = (const float*)d_in[7];
    const float* g2  = (const float*)d_in[8];
    const float* be2 = (const float*)d_in[9];
    const float* Wp  = (const float*)d_in[10];
    const float* bp  = (const float*)d_in[11];
    float* out = (float*)d_out;

    const int* tgt = ei;
    const int* src = ei + N_EDGES;

    char* ws = (char*)d_ws;
    int*   deg_i   = (int*)   ws;               ws += 40960 * 4;   // memset-zeroed
    int*   row_ptr = (int*)   ws;               ws += 41984 * 4;   // block-local scan
    int*   row_ptr_g = (int*) ws;               ws += 41984 * 4;   // globalized
    int*   partials= (int*)   ws;               ws += 256 * 4;
    int*   rank    = (int*)   ws;               ws += (size_t)N_EDGES * 4;
    int*   col     = (int*)   ws;               ws += (size_t)N_EDGES * 4;
    float* dis     = (float*) ws;               ws += 40960 * 4;
    unsigned short* x_bf   = (unsigned short*)ws; ws += (size_t)N_NODES * D * 2;
    unsigned short* tmp_bf = (unsigned short*)ws; ws += (size_t)N_NODES * D * 2;
    unsigned short* tmp2_bf= (unsigned short*)ws; ws += (size_t)N_NODES * D * 2;  // separate: no WAR race
    unsigned short* h1_bf  = (unsigned short*)ws; ws += (size_t)N_NODES * D * 2;
    unsigned short* W1t    = (unsigned short*)ws; ws += 128 * 128 * 2;
    unsigned short* W2t    = (unsigned short*)ws; ws += 128 * 128 * 2;
    unsigned short* Wpt    = (unsigned short*)ws; ws += 384 * 64 * 2;

    const int B = 256;

    hipMemsetAsync(deg_i, 0, 40960 * 4, stream);
    k_prep <<<5000, B, 0, stream>>>(x, W1, W2, Wp, tgt, deg_i, rank, x_bf, W1t, W2t, Wpt);
    k_scan1<<<SCAN_NBLK, B, 0, stream>>>(deg_i, row_ptr, partials, dis);

    // scatter (atomic-free) + gemm1 = dis*(x@W1), one dispatch
    k_scatter_gemm<<<3750, B, 0, stream>>>(tgt, src, row_ptr, partials,
                                           row_ptr_g, rank, col,
                                           x_bf, W1t, dis, tmp_bf);

    // agg1 (gathers tmp_bf) + LN -> h1_bf, fused gemm2 -> tmp2_bf
    k_agg_gemm2<<<2500, B, 0, stream>>>(tmp_bf, dis, row_ptr_g, col, b1, g1, be1,
                                        W2t, h1_bf, tmp2_bf);

    // agg2 (gathers tmp2_bf) + LN (LDS-resident h2) + fused projection
    k_agg_final<<<2500, B, 0, stream>>>(tmp2_bf, dis, row_ptr_g, col, b2, g2, be2,
                                        x_bf, h1_bf, Wpt, bp, out);
}